// Round 2
// baseline (1220.461 us; speedup 1.0000x reference)
//
#include <hip/hip_runtime.h>
#include <hip/hip_bf16.h>

#define R_TOT 8192
#define NX 32
#define NM 64
#define STRD 33
#define VSTRD 36
#define OPSTRD 36
#define WARM 16
#define CHUNKF 16
#define CHUNKB 16

template<typename T> __device__ inline T toST(float v);
template<> __device__ inline float toST<float>(float v) { return v; }
template<> __device__ inline __hip_bfloat16 toST<__hip_bfloat16>(float v) { return __float2bfloat16(v); }
__device__ inline float fromST(float v) { return v; }
__device__ inline float fromST(__hip_bfloat16 v) { return __bfloat162float(v); }

// single-wave "barrier": lockstep wave64 + drain LDS ops. Valid only for 64-thread blocks.
__device__ inline void wsync() { asm volatile("s_waitcnt lgkmcnt(0)" ::: "memory"); }

// ---------------- precompute ap = A@P, apat = ap@A^T (shared by all chunks) --------------
__global__ __launch_bounds__(64) void precomp_kernel(
    const float* __restrict__ A, const float* __restrict__ P,
    float* __restrict__ apG, float* __restrict__ apatG)
{
  __shared__ float As[NX*STRD], Ps[NX*STRD], aps[NX*STRD];
  const int t = threadIdx.x;
  for (int e = t; e < NX*NX; e += 64) {
    int i = e >> 5, j = e & 31;
    As[i*STRD+j] = A[e];
    Ps[i*STRD+j] = P[e];
  }
  wsync();
  for (int e = t; e < NX*NX; e += 64) {
    int i = e >> 5, j = e & 31;
    float s = 0.f;
    for (int k = 0; k < NX; ++k) s += As[i*STRD+k] * Ps[k*STRD+j];
    aps[i*STRD+j] = s;
    apG[e] = s;
  }
  wsync();
  for (int e = t; e < NX*NX; e += 64) {
    int i = e >> 5, j = e & 31;
    float s = 0.f;
    for (int k = 0; k < NX; ++k) s += aps[i*STRD+k] * As[j*STRD+k];
    apatG[e] = s;
  }
}

// ---------------- forward: chunked Riccati scan, register-heavy ----------------
// one wave per chunk. Lane owns elements (i = (t>>5)+2m, j = t&31), m=0..15.
// apP layout: apP[k*32 + 16*half + m] = ap[k][half+2m]  (m-sweep contiguous -> b128)
// offP layout: offP[k*OPSTRD + 16*half + m] = off[half+2m][k]
template<typename ST>
__global__ __launch_bounds__(64, 2) void fwd_kernel(
    const float* __restrict__ hessAll, const float* __restrict__ gradAll,
    const float* __restrict__ apG, const float* __restrict__ apatG,
    const float* __restrict__ P, const float* __restrict__ initP,
    ST* __restrict__ offOut, ST* __restrict__ xOut, float* __restrict__ uOut)
{
  __shared__ float apP[NX*32], sm[NX*STRD], xi[NX*STRD], off[NX*STRD], offP[NX*OPSTRD];
  __shared__ float uv[NX], tv[NX], dinv[NX], sqd[NX];
  const int t = threadIdx.x;
  const int lane = t & 31, half = t >> 5;
  const int c = blockIdx.x;
  const int r0 = c * CHUNKF, r1 = r0 + CHUNKF;

  float PsR[16], apatR[16], predR[16], hessR[16];
  float gradR;

  const int cl = 16*(lane & 1) + (lane >> 1);   // permuted-column map
  #pragma unroll
  for (int m = 0; m < 16; ++m) {
    int e = t + 64*m;
    apP[(half + 2*m)*32 + cl] = apG[e];
    PsR[m]   = P[e];
    apatR[m] = apatG[e];
  }
  wsync();

  int rstart = r0 - WARM;
  if (rstart < 0) rstart = 0;
  const bool exact = (rstart == 0);

  #pragma unroll
  for (int m = 0; m < 16; ++m) {
    predR[m] = exact ? initP[t + 64*m] : PsR[m];   // any SPD init works (contraction)
    off[(half + 2*m)*STRD + lane] = 0.f;
  }
  if (t < NX) uv[t] = 0.f;
  wsync();

  // preload first step's hess/grad
  {
    const float* hess = hessAll + (size_t)rstart * (NX*NX);
    #pragma unroll
    for (int m = 0; m < 16; ++m) hessR[m] = hess[t + 64*m];
    gradR = gradAll[(size_t)rstart * NX + lane];
  }

  for (int r = rstart; r < r1; ++r) {
    const bool last = (r == R_TOT-1);
    // ---- S = pred + hess (+ apat) into sm ----
    #pragma unroll
    for (int m = 0; m < 16; ++m) {
      float v = predR[m] + hessR[m];
      if (!last) v += apatR[m];
      sm[(half + 2*m)*STRD + lane] = v;
    }
    wsync();
    // prefetch next step's hess (consumed above; latency hidden under chol)
    if (r + 1 < r1) {
      const float* hn = hessAll + (size_t)(r+1) * (NX*NX);
      #pragma unroll
      for (int m = 0; m < 16; ++m) hessR[m] = hn[t + 64*m];
    }
    // ---- LDL^T, right-looking, unscaled columns: sm[i][j] = l~_ij * d_j ----
    #pragma unroll
    for (int j = 0; j < NX-1; ++j) {
      float invd = __builtin_amdgcn_rcpf(sm[j*STRD+j]);   // broadcast read + fast rcp
      int kk = j + 1 + lane;
      bool act = kk < NX;
      float f = act ? sm[kk*STRD+j] * invd : 0.f;
      #pragma unroll
      for (int m = 0; m < 16; ++m) {
        int ib = j + 1 + half + 2*m;
        if (ib < NX) {                       // compile-time dead for large m
          if (act && kk <= ib)
            sm[ib*STRD+kk] -= sm[ib*STRD+j] * f;
        }
      }
      wsync();
    }
    if (t < NX) { float d = sm[t*STRD+t]; dinv[t] = __builtin_amdgcn_rcpf(d); sqd[t] = sqrtf(d); }
    wsync();
    // ---- zeta = D^{-1} L~^{-1}; lane t holds column t; xi = chol^{-1} ----
    {
      float zc[NX];
      #pragma unroll
      for (int i = 0; i < NX; ++i) {
        float s = 0.f;
        #pragma unroll
        for (int k = 0; k < i; ++k) s += sm[i*STRD+k] * zc[k];   // broadcast reads
        float di = dinv[i];
        zc[i] = (i == t) ? di : -di * s;
      }
      if (t < NX) {
        if (r >= r0) {
          size_t base = (size_t)r * (NX*NX);
          #pragma unroll
          for (int i = 0; i < NX; ++i) {
            float v = zc[i] * sqd[i];
            xi[i*STRD + t] = v;
            xOut[base + i*NX + t] = toST<ST>(v);
          }
        } else {
          #pragma unroll
          for (int i = 0; i < NX; ++i) xi[i*STRD + t] = zc[i] * sqd[i];
        }
      }
    }
    wsync();
    // ---- u update: tv = grad - u_prev @ off_prev^T ; u_new = tv @ xi^T ----
    if (t < NX) {
      float s = gradR;
      #pragma unroll 4
      for (int m = 0; m < NX; ++m) s -= uv[m] * off[t*STRD+m];
      tv[t] = s;
    }
    wsync();
    float unew = 0.f;
    if (t < NX) {
      float s = 0.f;
      #pragma unroll 4
      for (int k = 0; k < NX; ++k) s += tv[k] * xi[t*STRD+k];
      unew = s;
    }
    wsync();
    if (t < NX) {
      uv[t] = unew;
      if (r >= r0) uOut[(size_t)r*NX + t] = unew;
    }
    if (r + 1 < r1) gradR = gradAll[(size_t)(r+1) * NX + lane];
    wsync();   // uv visible; off reads (u phase) drained before overwrite below
    // ---- off[jj][ii] = -sum_k xi[ii][k] ap[k][jj]; ii = lane, jj = half+2m ----
    {
      float offR[16];
      #pragma unroll
      for (int m = 0; m < 16; ++m) offR[m] = 0.f;
      #pragma unroll
      for (int k = 0; k < NX; ++k) {
        float xv = xi[lane*STRD + k];            // conflict-free
        const float4* apv = reinterpret_cast<const float4*>(&apP[k*32 + 16*half]);
        float4 a0 = apv[0], a1 = apv[1], a2 = apv[2], a3 = apv[3];   // broadcast b128
        offR[0]  += xv * a0.x; offR[1]  += xv * a0.y; offR[2]  += xv * a0.z; offR[3]  += xv * a0.w;
        offR[4]  += xv * a1.x; offR[5]  += xv * a1.y; offR[6]  += xv * a1.z; offR[7]  += xv * a1.w;
        offR[8]  += xv * a2.x; offR[9]  += xv * a2.y; offR[10] += xv * a2.z; offR[11] += xv * a2.w;
        offR[12] += xv * a3.x; offR[13] += xv * a3.y; offR[14] += xv * a3.z; offR[15] += xv * a3.w;
      }
      if (r >= r0) {
        size_t base = (size_t)r * (NX*NX);
        #pragma unroll
        for (int m = 0; m < 16; ++m) {
          float v = -offR[m];
          off[(half + 2*m)*STRD + lane] = v;
          offOut[base + (half + 2*m)*NX + lane] = toST<ST>(v);
        }
      } else {
        #pragma unroll
        for (int m = 0; m < 16; ++m)
          off[(half + 2*m)*STRD + lane] = -offR[m];
      }
      // offP[k=lane][16*half + m] = off[half+2m][lane]  (contiguous per lane -> b128)
      float4* opw = reinterpret_cast<float4*>(&offP[lane*OPSTRD + 16*half]);
      opw[0] = make_float4(-offR[0],  -offR[1],  -offR[2],  -offR[3]);
      opw[1] = make_float4(-offR[4],  -offR[5],  -offR[6],  -offR[7]);
      opw[2] = make_float4(-offR[8],  -offR[9],  -offR[10], -offR[11]);
      opw[3] = make_float4(-offR[12], -offR[13], -offR[14], -offR[15]);
    }
    wsync();
    // ---- pred = P - off @ off^T (into registers) ----
    #pragma unroll
    for (int m = 0; m < 16; ++m) predR[m] = PsR[m];
    #pragma unroll
    for (int k = 0; k < NX; ++k) {
      float fj = off[lane*STRD + k];             // conflict-free
      const float4* ov = reinterpret_cast<const float4*>(&offP[k*OPSTRD + 16*half]);
      float4 o0 = ov[0], o1 = ov[1], o2 = ov[2], o3 = ov[3];   // broadcast b128
      predR[0]  -= o0.x*fj; predR[1]  -= o0.y*fj; predR[2]  -= o0.z*fj; predR[3]  -= o0.w*fj;
      predR[4]  -= o1.x*fj; predR[5]  -= o1.y*fj; predR[6]  -= o1.z*fj; predR[7]  -= o1.w*fj;
      predR[8]  -= o2.x*fj; predR[9]  -= o2.y*fj; predR[10] -= o2.z*fj; predR[11] -= o2.w*fj;
      predR[12] -= o3.x*fj; predR[13] -= o3.y*fj; predR[14] -= o3.z*fj; predR[15] -= o3.w*fj;
    }
    wsync();
  }
}

// ---------------- backward: chunked reverse linear scan ----------------
// 256 threads/chunk. Thread owns rows i = grp+8m (grp = t>>5), col j = t&31.
// vw/bb use stride VSTRD=36 so rows are 16B-aligned -> b128 broadcast reads.
template<typename ST>
__global__ __launch_bounds__(256, 4) void bwd_kernel(
    const ST* __restrict__ offIn, const ST* __restrict__ xIn, const float* __restrict__ uIn,
    const float* __restrict__ epsx, float* __restrict__ outp)
{
  __shared__ float vw[(NM+1)*VSTRD], bb[(NM+1)*VSTRD], off[NX*STRD], xi[NX*STRD];
  const int t = threadIdx.x;
  const int lane = t & 31, grp = t >> 5;
  const int c = blockIdx.x;
  const int r0 = c * CHUNKB, r1 = r0 + CHUNKB;
  int rstart = r1 + WARM; if (rstart > R_TOT) rstart = R_TOT;
  const bool has64 = (grp == 0);

  for (int e = t; e < (NM+1)*VSTRD; e += 256) vw[e] = 0.f;

  float offR[4], xiR[4], gR[9];
  {
    int r = rstart - 1;
    size_t base = (size_t)r * (NX*NX);
    #pragma unroll
    for (int m = 0; m < 4; ++m) {
      offR[m] = fromST(offIn[base + t + 256*m]);
      xiR[m]  = fromST(xIn[base + t + 256*m]);
    }
    const float* eps_r = epsx + (size_t)r * (NM*NX);
    const float* u_r   = uIn + (size_t)r * NX;
    #pragma unroll
    for (int m = 0; m < 8; ++m) {
      int i = grp + 8*m;
      gR[m] = (i == 0) ? u_r[lane] : eps_r[(i-1)*NX + lane];
    }
    gR[8] = has64 ? eps_r[63*NX + lane] : 0.f;
  }
  __syncthreads();

  for (int r = rstart - 1; r >= r0; --r) {
    // deposit this step's off/xi; move g into acc
    float acc[9];
    #pragma unroll
    for (int m = 0; m < 9; ++m) acc[m] = gR[m];
    #pragma unroll
    for (int m = 0; m < 4; ++m) {
      off[(grp + 8*m)*STRD + lane] = offR[m];
      xi[(grp + 8*m)*STRD + lane]  = xiR[m];
    }
    __syncthreads();
    // prefetch next (lower) step's inputs
    if (r > r0) {
      size_t base = (size_t)(r-1) * (NX*NX);
      #pragma unroll
      for (int m = 0; m < 4; ++m) {
        offR[m] = fromST(offIn[base + t + 256*m]);
        xiR[m]  = fromST(xIn[base + t + 256*m]);
      }
      const float* eps_n = epsx + (size_t)(r-1) * (NM*NX);
      const float* u_n   = uIn + (size_t)(r-1) * NX;
      #pragma unroll
      for (int m = 0; m < 8; ++m) {
        int i = grp + 8*m;
        gR[m] = (i == 0) ? u_n[lane] : eps_n[(i-1)*NX + lane];
      }
      if (has64) gR[8] = eps_n[63*NX + lane];
    }
    // ---- bb = g - vw @ off : hoist off column into regs, b128 the vw rows ----
    float fo[NX];
    #pragma unroll
    for (int k = 0; k < NX; ++k) fo[k] = off[k*STRD + lane];   // conflict-free
    #pragma unroll
    for (int m = 0; m < 8; ++m) {
      const float4* vr = reinterpret_cast<const float4*>(&vw[(grp + 8*m)*VSTRD]);
      #pragma unroll
      for (int q = 0; q < 8; ++q) {
        float4 v4 = vr[q];                    // broadcast b128
        acc[m] -= v4.x*fo[4*q] + v4.y*fo[4*q+1] + v4.z*fo[4*q+2] + v4.w*fo[4*q+3];
      }
    }
    if (has64) {
      const float4* vr = reinterpret_cast<const float4*>(&vw[64*VSTRD]);
      #pragma unroll
      for (int q = 0; q < 8; ++q) {
        float4 v4 = vr[q];
        acc[8] -= v4.x*fo[4*q] + v4.y*fo[4*q+1] + v4.z*fo[4*q+2] + v4.w*fo[4*q+3];
      }
    }
    #pragma unroll
    for (int m = 0; m < 8; ++m) bb[(grp + 8*m)*VSTRD + lane] = acc[m];
    if (has64) bb[64*VSTRD + lane] = acc[8];
    __syncthreads();
    // ---- vw = bb @ xi : hoist xi column into regs, b128 the bb rows ----
    float fx[NX];
    #pragma unroll
    for (int k = 0; k < NX; ++k) fx[k] = xi[k*STRD + lane];    // conflict-free
    float vacc[9];
    #pragma unroll
    for (int m = 0; m < 9; ++m) vacc[m] = 0.f;
    #pragma unroll
    for (int m = 0; m < 8; ++m) {
      const float4* br = reinterpret_cast<const float4*>(&bb[(grp + 8*m)*VSTRD]);
      #pragma unroll
      for (int q = 0; q < 8; ++q) {
        float4 b4 = br[q];                    // broadcast b128
        vacc[m] += b4.x*fx[4*q] + b4.y*fx[4*q+1] + b4.z*fx[4*q+2] + b4.w*fx[4*q+3];
      }
    }
    if (has64) {
      const float4* br = reinterpret_cast<const float4*>(&bb[64*VSTRD]);
      #pragma unroll
      for (int q = 0; q < 8; ++q) {
        float4 b4 = br[q];
        vacc[8] += b4.x*fx[4*q] + b4.y*fx[4*q+1] + b4.z*fx[4*q+2] + b4.w*fx[4*q+3];
      }
    }
    #pragma unroll
    for (int m = 0; m < 8; ++m) vw[(grp + 8*m)*VSTRD + lane] = vacc[m];
    if (has64) vw[64*VSTRD + lane] = vacc[8];
    __syncthreads();
    // ---- out_r[i][j] = vw[i+1][j] + vw[0][j], rows i = grp+8m ----
    if (r < r1) {
      float v0 = vw[lane];
      float* out_r = outp + (size_t)r * (NM*NX);
      #pragma unroll
      for (int m = 0; m < 8; ++m)
        out_r[(grp + 8*m)*NX + lane] = vw[(grp + 8*m + 1)*VSTRD + lane] + v0;
    }
    __syncthreads();
  }
}

extern "C" void kernel_launch(void* const* d_in, const int* in_sizes, int n_in,
                              void* d_out, int out_size, void* d_ws, size_t ws_size,
                              hipStream_t stream) {
  const float* hess  = (const float*)d_in[0];
  const float* grads = (const float*)d_in[1];
  const float* A     = (const float*)d_in[2];
  const float* P     = (const float*)d_in[3];
  const float* initP = (const float*)d_in[4];
  const float* epsx  = (const float*)d_in[5];
  float* outp = (float*)d_out;

  const size_t mats = (size_t)R_TOT * NX * NX;
  const size_t uN   = (size_t)R_TOT * NX;
  const size_t needF32 = 2ull * mats * sizeof(float) + uN * sizeof(float) + 2048 * sizeof(float);

  if (ws_size >= needF32) {
    float* offS  = (float*)d_ws;
    float* xS    = offS + mats;
    float* uS    = xS + mats;
    float* apG   = uS + uN;
    float* apatG = apG + 1024;
    precomp_kernel<<<dim3(1), dim3(64), 0, stream>>>(A, P, apG, apatG);
    fwd_kernel<float><<<dim3(R_TOT/CHUNKF), dim3(64), 0, stream>>>(
        hess, grads, apG, apatG, P, initP, offS, xS, uS);
    bwd_kernel<float><<<dim3(R_TOT/CHUNKB), dim3(256), 0, stream>>>(
        offS, xS, uS, epsx, outp);
  } else {
    __hip_bfloat16* offS = (__hip_bfloat16*)d_ws;
    __hip_bfloat16* xS   = offS + mats;
    float* uS            = (float*)(xS + mats);
    float* apG           = uS + uN;
    float* apatG         = apG + 1024;
    precomp_kernel<<<dim3(1), dim3(64), 0, stream>>>(A, P, apG, apatG);
    fwd_kernel<__hip_bfloat16><<<dim3(R_TOT/CHUNKF), dim3(64), 0, stream>>>(
        hess, grads, apG, apatG, P, initP, offS, xS, uS);
    bwd_kernel<__hip_bfloat16><<<dim3(R_TOT/CHUNKB), dim3(256), 0, stream>>>(
        offS, xS, uS, epsx, outp);
  }
}

// Round 3
// 632.337 us; speedup vs baseline: 1.9301x; 1.9301x over previous
//
#include <hip/hip_runtime.h>
#include <hip/hip_bf16.h>

#define R_TOT 8192
#define NX 32
#define NM 64
#define STRD 33
#define VSTRD 36
#define OPSTRD 36
#define WARM 16
#define CHUNKF 4
#define CHUNKB 16

template<typename T> __device__ inline T toST(float v);
template<> __device__ inline float toST<float>(float v) { return v; }
template<> __device__ inline __hip_bfloat16 toST<__hip_bfloat16>(float v) { return __float2bfloat16(v); }
__device__ inline float fromST(float v) { return v; }
__device__ inline float fromST(__hip_bfloat16 v) { return __bfloat162float(v); }

// single-wave "barrier": lockstep wave64 + drain LDS ops. Valid only for 64-thread blocks.
__device__ inline void wsync() { asm volatile("s_waitcnt lgkmcnt(0)" ::: "memory"); }

// wave-uniform broadcast of lane l's value (l must be wave-uniform; here compile-time)
__device__ inline float rdlane(float v, int l) {
  return __uint_as_float(__builtin_amdgcn_readlane(__float_as_uint(v), l));
}

// ---------------- precompute ap = A@P, apat = ap@A^T (shared by all chunks) --------------
__global__ __launch_bounds__(64) void precomp_kernel(
    const float* __restrict__ A, const float* __restrict__ P,
    float* __restrict__ apG, float* __restrict__ apatG)
{
  __shared__ float As[NX*STRD], Ps[NX*STRD], aps[NX*STRD];
  const int t = threadIdx.x;
  for (int e = t; e < NX*NX; e += 64) {
    int i = e >> 5, j = e & 31;
    As[i*STRD+j] = A[e];
    Ps[i*STRD+j] = P[e];
  }
  wsync();
  for (int e = t; e < NX*NX; e += 64) {
    int i = e >> 5, j = e & 31;
    float s = 0.f;
    for (int k = 0; k < NX; ++k) s += As[i*STRD+k] * Ps[k*STRD+j];
    aps[i*STRD+j] = s;
    apG[e] = s;
  }
  wsync();
  for (int e = t; e < NX*NX; e += 64) {
    int i = e >> 5, j = e & 31;
    float s = 0.f;
    for (int k = 0; k < NX; ++k) s += aps[i*STRD+k] * As[j*STRD+k];
    apatG[e] = s;
  }
}

// ---------------- forward: chunked Riccati scan ----------------
// one wave per chunk. Matmul phases: lane owns (i = half+2m, j = lane), m=0..15.
// LDL/zeta: full-row register layout (lane r = t&31 owns row r in 32 VGPRs; upper
// half-wave mirrors), broadcasts via v_readlane -> zero LDS traffic, ~1K cy chain.
// apP layout: apP[k*32 + 16*half + m] = ap[k][half+2m]  (m-sweep contiguous -> b128)
// offP layout: offP[k*OPSTRD + 16*half + m] = off[half+2m][k]; aliased onto sm buffer
// (sm is only live S-phase->row-load; offP only off-phase->pred-phase).
template<typename ST>
__global__ __launch_bounds__(64, 2) void fwd_kernel(
    const float* __restrict__ hessAll, const float* __restrict__ gradAll,
    const float* __restrict__ apG, const float* __restrict__ apatG,
    const float* __restrict__ P, const float* __restrict__ initP,
    ST* __restrict__ offOut, ST* __restrict__ xOut, float* __restrict__ uOut)
{
  __shared__ float apP[NX*32], scratch[NX*OPSTRD], xi[NX*STRD], off[NX*STRD];
  __shared__ float uv[NX], tv[NX];
  float* const sm   = scratch;   // stride STRD (33): 1056 floats <= 1152
  float* const offP = scratch;   // stride OPSTRD (36): disjoint lifetime vs sm
  const int t = threadIdx.x;
  const int lane = t & 31, half = t >> 5;
  const int c = blockIdx.x;
  const int r0 = c * CHUNKF, r1 = r0 + CHUNKF;

  float PsR[16], apatR[16], predR[16], hessR[16];
  float gradR;

  const int cl = 16*(lane & 1) + (lane >> 1);   // permuted-column map
  #pragma unroll
  for (int m = 0; m < 16; ++m) {
    int e = t + 64*m;
    apP[(half + 2*m)*32 + cl] = apG[e];
    PsR[m]   = P[e];
    apatR[m] = apatG[e];
  }
  wsync();

  int rstart = r0 - WARM;
  if (rstart < 0) rstart = 0;
  const bool exact = (rstart == 0);

  #pragma unroll
  for (int m = 0; m < 16; ++m) {
    predR[m] = exact ? initP[t + 64*m] : PsR[m];   // any SPD init works (contraction)
    off[(half + 2*m)*STRD + lane] = 0.f;
  }
  if (t < NX) uv[t] = 0.f;
  wsync();

  // preload first step's hess/grad
  {
    const float* hess = hessAll + (size_t)rstart * (NX*NX);
    #pragma unroll
    for (int m = 0; m < 16; ++m) hessR[m] = hess[t + 64*m];
    gradR = gradAll[(size_t)rstart * NX + lane];
  }

  for (int r = rstart; r < r1; ++r) {
    const bool last = (r == R_TOT-1);
    // ---- S = pred + hess (+ apat) into sm (transpose buffer) ----
    #pragma unroll
    for (int m = 0; m < 16; ++m) {
      float v = predR[m] + hessR[m];
      if (!last) v += apatR[m];
      sm[(half + 2*m)*STRD + lane] = v;
    }
    wsync();
    // prefetch next step's hess (latency hidden under LDL/zeta)
    if (r + 1 < r1) {
      const float* hn = hessAll + (size_t)(r+1) * (NX*NX);
      #pragma unroll
      for (int m = 0; m < 16; ++m) hessR[m] = hn[t + 64*m];
    }
    // ---- row-load: lane r = t&31 takes row r (upper half mirrors, broadcast reads) ----
    float row[NX];
    #pragma unroll
    for (int k = 0; k < NX; ++k) row[k] = sm[lane*STRD + k];
    // ---- LDL^T in registers, right-looking, unscaled columns: row[c] = l~_rc * d_c ----
    // lane r>j: f = row[j]*invd; row-j broadcast via readlane -> SGPR operand FMA.
    #pragma unroll
    for (int j = 0; j < NX-1; ++j) {
      float invd = __builtin_amdgcn_rcpf(rdlane(row[j], j));
      float f = (lane > j) ? row[j] * invd : 0.f;
      #pragma unroll
      for (int cc = j+1; cc < NX; ++cc)
        row[cc] = fmaf(-f, rdlane(row[cc], j), row[cc]);
    }
    // ---- zeta = D^{-1} L~^{-1} (column t per lane), all operands via readlane ----
    {
      size_t base = (size_t)r * (NX*NX);
      float zc[NX];
      #pragma unroll
      for (int i = 0; i < NX; ++i) {
        float d_i = rdlane(row[i], i);
        float di = __builtin_amdgcn_rcpf(d_i);
        float s = 0.f;
        #pragma unroll
        for (int k = 0; k < i; ++k) s = fmaf(rdlane(row[k], i), zc[k], s);
        zc[i] = (i == lane) ? di : -di * s;
        float v = zc[i] * sqrtf(d_i);          // xi = chol^{-1} row i, col t
        if (t < NX) {
          xi[i*STRD + t] = v;
          if (r >= r0) xOut[base + i*NX + t] = toST<ST>(v);
        }
      }
    }
    wsync();
    // ---- u update: tv = grad - u_prev @ off_prev^T ; u_new = tv @ xi^T ----
    if (t < NX) {
      float s = gradR;
      #pragma unroll 4
      for (int m = 0; m < NX; ++m) s -= uv[m] * off[t*STRD+m];
      tv[t] = s;
    }
    wsync();
    float unew = 0.f;
    if (t < NX) {
      float s = 0.f;
      #pragma unroll 4
      for (int k = 0; k < NX; ++k) s += tv[k] * xi[t*STRD+k];
      unew = s;
    }
    wsync();
    if (t < NX) {
      uv[t] = unew;
      if (r >= r0) uOut[(size_t)r*NX + t] = unew;
    }
    if (r + 1 < r1) gradR = gradAll[(size_t)(r+1) * NX + lane];
    wsync();   // uv visible; off reads (u phase) drained before overwrite below
    // ---- off[jj][ii] = -sum_k xi[ii][k] ap[k][jj]; ii = lane, jj = half+2m ----
    {
      float offR[16];
      #pragma unroll
      for (int m = 0; m < 16; ++m) offR[m] = 0.f;
      #pragma unroll
      for (int k = 0; k < NX; ++k) {
        float xv = xi[lane*STRD + k];            // conflict-free
        const float4* apv = reinterpret_cast<const float4*>(&apP[k*32 + 16*half]);
        float4 a0 = apv[0], a1 = apv[1], a2 = apv[2], a3 = apv[3];   // broadcast b128
        offR[0]  += xv * a0.x; offR[1]  += xv * a0.y; offR[2]  += xv * a0.z; offR[3]  += xv * a0.w;
        offR[4]  += xv * a1.x; offR[5]  += xv * a1.y; offR[6]  += xv * a1.z; offR[7]  += xv * a1.w;
        offR[8]  += xv * a2.x; offR[9]  += xv * a2.y; offR[10] += xv * a2.z; offR[11] += xv * a2.w;
        offR[12] += xv * a3.x; offR[13] += xv * a3.y; offR[14] += xv * a3.z; offR[15] += xv * a3.w;
      }
      if (r >= r0) {
        size_t base = (size_t)r * (NX*NX);
        #pragma unroll
        for (int m = 0; m < 16; ++m) {
          float v = -offR[m];
          off[(half + 2*m)*STRD + lane] = v;
          offOut[base + (half + 2*m)*NX + lane] = toST<ST>(v);
        }
      } else {
        #pragma unroll
        for (int m = 0; m < 16; ++m)
          off[(half + 2*m)*STRD + lane] = -offR[m];
      }
      // offP[k=lane][16*half + m] = off[half+2m][lane]  (contiguous per lane -> b128)
      float4* opw = reinterpret_cast<float4*>(&offP[lane*OPSTRD + 16*half]);
      opw[0] = make_float4(-offR[0],  -offR[1],  -offR[2],  -offR[3]);
      opw[1] = make_float4(-offR[4],  -offR[5],  -offR[6],  -offR[7]);
      opw[2] = make_float4(-offR[8],  -offR[9],  -offR[10], -offR[11]);
      opw[3] = make_float4(-offR[12], -offR[13], -offR[14], -offR[15]);
    }
    wsync();
    // ---- pred = P - off @ off^T (into registers) ----
    #pragma unroll
    for (int m = 0; m < 16; ++m) predR[m] = PsR[m];
    #pragma unroll
    for (int k = 0; k < NX; ++k) {
      float fj = off[lane*STRD + k];             // conflict-free
      const float4* ov = reinterpret_cast<const float4*>(&offP[k*OPSTRD + 16*half]);
      float4 o0 = ov[0], o1 = ov[1], o2 = ov[2], o3 = ov[3];   // broadcast b128
      predR[0]  -= o0.x*fj; predR[1]  -= o0.y*fj; predR[2]  -= o0.z*fj; predR[3]  -= o0.w*fj;
      predR[4]  -= o1.x*fj; predR[5]  -= o1.y*fj; predR[6]  -= o1.z*fj; predR[7]  -= o1.w*fj;
      predR[8]  -= o2.x*fj; predR[9]  -= o2.y*fj; predR[10] -= o2.z*fj; predR[11] -= o2.w*fj;
      predR[12] -= o3.x*fj; predR[13] -= o3.y*fj; predR[14] -= o3.z*fj; predR[15] -= o3.w*fj;
    }
    wsync();   // offP reads drained before next step's sm overwrite (aliased buffer)
  }
}

// ---------------- backward: chunked reverse linear scan ----------------
// 256 threads/chunk. Thread owns rows i = grp+8m (grp = t>>5), col j = t&31.
// vw/bb use stride VSTRD=36 so rows are 16B-aligned -> b128 broadcast reads.
template<typename ST>
__global__ __launch_bounds__(256, 4) void bwd_kernel(
    const ST* __restrict__ offIn, const ST* __restrict__ xIn, const float* __restrict__ uIn,
    const float* __restrict__ epsx, float* __restrict__ outp)
{
  __shared__ float vw[(NM+1)*VSTRD], bb[(NM+1)*VSTRD], off[NX*STRD], xi[NX*STRD];
  const int t = threadIdx.x;
  const int lane = t & 31, grp = t >> 5;
  const int c = blockIdx.x;
  const int r0 = c * CHUNKB, r1 = r0 + CHUNKB;
  int rstart = r1 + WARM; if (rstart > R_TOT) rstart = R_TOT;
  const bool has64 = (grp == 0);

  for (int e = t; e < (NM+1)*VSTRD; e += 256) vw[e] = 0.f;

  float offR[4], xiR[4], gR[9];
  {
    int r = rstart - 1;
    size_t base = (size_t)r * (NX*NX);
    #pragma unroll
    for (int m = 0; m < 4; ++m) {
      offR[m] = fromST(offIn[base + t + 256*m]);
      xiR[m]  = fromST(xIn[base + t + 256*m]);
    }
    const float* eps_r = epsx + (size_t)r * (NM*NX);
    const float* u_r   = uIn + (size_t)r * NX;
    #pragma unroll
    for (int m = 0; m < 8; ++m) {
      int i = grp + 8*m;
      gR[m] = (i == 0) ? u_r[lane] : eps_r[(i-1)*NX + lane];
    }
    gR[8] = has64 ? eps_r[63*NX + lane] : 0.f;
  }
  __syncthreads();

  for (int r = rstart - 1; r >= r0; --r) {
    // deposit this step's off/xi; move g into acc
    float acc[9];
    #pragma unroll
    for (int m = 0; m < 9; ++m) acc[m] = gR[m];
    #pragma unroll
    for (int m = 0; m < 4; ++m) {
      off[(grp + 8*m)*STRD + lane] = offR[m];
      xi[(grp + 8*m)*STRD + lane]  = xiR[m];
    }
    __syncthreads();
    // prefetch next (lower) step's inputs
    if (r > r0) {
      size_t base = (size_t)(r-1) * (NX*NX);
      #pragma unroll
      for (int m = 0; m < 4; ++m) {
        offR[m] = fromST(offIn[base + t + 256*m]);
        xiR[m]  = fromST(xIn[base + t + 256*m]);
      }
      const float* eps_n = epsx + (size_t)(r-1) * (NM*NX);
      const float* u_n   = uIn + (size_t)(r-1) * NX;
      #pragma unroll
      for (int m = 0; m < 8; ++m) {
        int i = grp + 8*m;
        gR[m] = (i == 0) ? u_n[lane] : eps_n[(i-1)*NX + lane];
      }
      if (has64) gR[8] = eps_n[63*NX + lane];
    }
    // ---- bb = g - vw @ off : hoist off column into regs, b128 the vw rows ----
    float fo[NX];
    #pragma unroll
    for (int k = 0; k < NX; ++k) fo[k] = off[k*STRD + lane];   // conflict-free
    #pragma unroll
    for (int m = 0; m < 8; ++m) {
      const float4* vr = reinterpret_cast<const float4*>(&vw[(grp + 8*m)*VSTRD]);
      #pragma unroll
      for (int q = 0; q < 8; ++q) {
        float4 v4 = vr[q];                    // broadcast b128
        acc[m] -= v4.x*fo[4*q] + v4.y*fo[4*q+1] + v4.z*fo[4*q+2] + v4.w*fo[4*q+3];
      }
    }
    if (has64) {
      const float4* vr = reinterpret_cast<const float4*>(&vw[64*VSTRD]);
      #pragma unroll
      for (int q = 0; q < 8; ++q) {
        float4 v4 = vr[q];
        acc[8] -= v4.x*fo[4*q] + v4.y*fo[4*q+1] + v4.z*fo[4*q+2] + v4.w*fo[4*q+3];
      }
    }
    #pragma unroll
    for (int m = 0; m < 8; ++m) bb[(grp + 8*m)*VSTRD + lane] = acc[m];
    if (has64) bb[64*VSTRD + lane] = acc[8];
    __syncthreads();
    // ---- vw = bb @ xi : hoist xi column into regs, b128 the bb rows ----
    float fx[NX];
    #pragma unroll
    for (int k = 0; k < NX; ++k) fx[k] = xi[k*STRD + lane];    // conflict-free
    float vacc[9];
    #pragma unroll
    for (int m = 0; m < 9; ++m) vacc[m] = 0.f;
    #pragma unroll
    for (int m = 0; m < 8; ++m) {
      const float4* br = reinterpret_cast<const float4*>(&bb[(grp + 8*m)*VSTRD]);
      #pragma unroll
      for (int q = 0; q < 8; ++q) {
        float4 b4 = br[q];                    // broadcast b128
        vacc[m] += b4.x*fx[4*q] + b4.y*fx[4*q+1] + b4.z*fx[4*q+2] + b4.w*fx[4*q+3];
      }
    }
    if (has64) {
      const float4* br = reinterpret_cast<const float4*>(&bb[64*VSTRD]);
      #pragma unroll
      for (int q = 0; q < 8; ++q) {
        float4 b4 = br[q];
        vacc[8] += b4.x*fx[4*q] + b4.y*fx[4*q+1] + b4.z*fx[4*q+2] + b4.w*fx[4*q+3];
      }
    }
    #pragma unroll
    for (int m = 0; m < 8; ++m) vw[(grp + 8*m)*VSTRD + lane] = vacc[m];
    if (has64) vw[64*VSTRD + lane] = vacc[8];
    __syncthreads();
    // ---- out_r[i][j] = vw[i+1][j] + vw[0][j], rows i = grp+8m ----
    if (r < r1) {
      float v0 = vw[lane];
      float* out_r = outp + (size_t)r * (NM*NX);
      #pragma unroll
      for (int m = 0; m < 8; ++m)
        out_r[(grp + 8*m)*NX + lane] = vw[(grp + 8*m + 1)*VSTRD + lane] + v0;
    }
    __syncthreads();
  }
}

extern "C" void kernel_launch(void* const* d_in, const int* in_sizes, int n_in,
                              void* d_out, int out_size, void* d_ws, size_t ws_size,
                              hipStream_t stream) {
  const float* hess  = (const float*)d_in[0];
  const float* grads = (const float*)d_in[1];
  const float* A     = (const float*)d_in[2];
  const float* P     = (const float*)d_in[3];
  const float* initP = (const float*)d_in[4];
  const float* epsx  = (const float*)d_in[5];
  float* outp = (float*)d_out;

  const size_t mats = (size_t)R_TOT * NX * NX;
  const size_t uN   = (size_t)R_TOT * NX;
  const size_t needF32 = 2ull * mats * sizeof(float) + uN * sizeof(float) + 2048 * sizeof(float);

  if (ws_size >= needF32) {
    float* offS  = (float*)d_ws;
    float* xS    = offS + mats;
    float* uS    = xS + mats;
    float* apG   = uS + uN;
    float* apatG = apG + 1024;
    precomp_kernel<<<dim3(1), dim3(64), 0, stream>>>(A, P, apG, apatG);
    fwd_kernel<float><<<dim3(R_TOT/CHUNKF), dim3(64), 0, stream>>>(
        hess, grads, apG, apatG, P, initP, offS, xS, uS);
    bwd_kernel<float><<<dim3(R_TOT/CHUNKB), dim3(256), 0, stream>>>(
        offS, xS, uS, epsx, outp);
  } else {
    __hip_bfloat16* offS = (__hip_bfloat16*)d_ws;
    __hip_bfloat16* xS   = offS + mats;
    float* uS            = (float*)(xS + mats);
    float* apG           = uS + uN;
    float* apatG         = apG + 1024;
    precomp_kernel<<<dim3(1), dim3(64), 0, stream>>>(A, P, apG, apatG);
    fwd_kernel<__hip_bfloat16><<<dim3(R_TOT/CHUNKF), dim3(64), 0, stream>>>(
        hess, grads, apG, apatG, P, initP, offS, xS, uS);
    bwd_kernel<__hip_bfloat16><<<dim3(R_TOT/CHUNKB), dim3(256), 0, stream>>>(
        offS, xS, uS, epsx, outp);
  }
}